// Round 2
// 75.661 us; speedup vs baseline: 1.0610x; 1.0610x over previous
//
#include <hip/hip_runtime.h>
#include <math.h>

#define N_LAYERS 5
#define NG 20

// ---------------------------------------------------------------------------
// Pre-kernel: compose the 20 shared U3 gates + ring CNOTs into one 16x16
// complex unitary W, stored interleaved (re,im) in d_ws: W[(j*16+k)*2 + {0,1}]
// = <j| U |k>.
//
// v2: one 256-thread block, ONE amplitude per thread (thread = col*16 + row),
// butterflies via __shfl_xor across the row bits, CNOT row-permutation via
// shuffled selects. Layer loop is ROLLED (#pragma unroll 1) so the code body
// is ~1.5 KB instead of ~21 KB of straight-line unrolled code — the v1 kernel
// was 94% stalled on serial cold-I$ misses (FETCH_SIZE 21 KB == code size,
// VALUBusy 0.006%, 63.5 us for 2 KB of output).
// ---------------------------------------------------------------------------
__global__ __launch_bounds__(256) void compose_W(const float* __restrict__ w,
                                                 float* __restrict__ W) {
    __shared__ float g[NG][8];
    const int t = threadIdx.x;
    if (t < NG) {
        float th = w[t * 3 + 0], ph = w[t * 3 + 1], la = w[t * 3 + 2];
        float st, ct, sl, cl, sp, cp, spl, cpl;
        sincosf(th * 0.5f, &st, &ct);
        sincosf(la, &sl, &cl);
        sincosf(ph, &sp, &cp);
        sincosf(ph + la, &spl, &cpl);
        g[t][0] = ct;        g[t][1] = 0.0f;
        g[t][2] = -cl * st;  g[t][3] = -sl * st;
        g[t][4] = cp * st;   g[t][5] = sp * st;
        g[t][6] = cpl * ct;  g[t][7] = spl * ct;
    }
    __syncthreads();

    const int row = t & 15;   // state basis index (wire0 = bit3)
    const int col = t >> 4;   // which basis column we propagate

    float wr = (row == col) ? 1.0f : 0.0f;
    float wi = 0.0f;

#pragma unroll 1            // rolled: keep code ~1.5 KB, 5 iterations re-hit I$
    for (int l = 0; l < N_LAYERS; ++l) {
#pragma unroll
        for (int q = 0; q < 4; ++q) {
            const float* gm = g[l * 4 + q];
            const float m00r = gm[0];
            const float m01r = gm[2], m01i = gm[3];
            const float m10r = gm[4], m10i = gm[5];
            const float m11r = gm[6], m11i = gm[7];
            const int stride = 8 >> q;          // row bit for this wire

            const float pr = __shfl_xor(wr, stride, 64);
            const float pi = __shfl_xor(wi, stride, 64);
            const bool up = (row & stride) != 0;

            // lower:  new = m00*mine + m01*partner   (m00 imag == 0)
            // upper:  new = m11*mine + m10*partner
            const float cAr = up ? m11r : m00r;
            const float cAi = up ? m11i : 0.0f;
            const float cBr = up ? m10r : m01r;
            const float cBi = up ? m10i : m01i;

            const float nr = cAr * wr - cAi * wi + cBr * pr - cBi * pi;
            const float ni = cAr * wi + cAi * wr + cBr * pi + cBi * pr;
            wr = nr; wi = ni;
        }
        // ring CNOTs (0,1)(1,2)(2,3)(3,0): row permutation
        // new[row] = old[row ^ tm] if (row & cm) else old[row]
#pragma unroll
        for (int e = 0; e < 4; ++e) {
            const int cm = 8 >> e;
            const int tm = 8 >> ((e + 1) & 3);
            const float pr = __shfl_xor(wr, tm, 64);
            const float pi = __shfl_xor(wi, tm, 64);
            if (row & cm) { wr = pr; wi = pi; }
        }
    }

    W[(row * 16 + col) * 2 + 0] = wr;
    W[(row * 16 + col) * 2 + 1] = wi;
}

// ---------------------------------------------------------------------------
// Main kernel (unchanged): per sample, build psi0 = v0 (x) v1 (x) v2 (x) v3
// from native sincos, then psi = W * psi0 (W via uniform s_loads -> SGPR
// operands), probs, butterfly +/- reduction to <Z_i>.
// ---------------------------------------------------------------------------
__global__ __launch_bounds__(256) void qmain(const float* __restrict__ x,
                                             const float* __restrict__ W,
                                             float* __restrict__ out) {
    const int b = blockIdx.x * 256 + threadIdx.x;
    const float4 xv = ((const float4*)x)[b];
    const float xs[4] = {xv.x, xv.y, xv.z, xv.w};

    // encoding columns: [cos(x/2), e^{ix} sin(x/2)]
    float vr[4][2], vi[4][2];
#pragma unroll
    for (int i = 0; i < 4; i++) {
        const float st = __sinf(xs[i] * 0.5f);
        const float ct = __cosf(xs[i] * 0.5f);
        const float sx = __sinf(xs[i]);
        const float cx = __cosf(xs[i]);
        vr[i][0] = ct;      vi[i][0] = 0.0f;
        vr[i][1] = cx * st; vi[i][1] = sx * st;
    }

    // tensor product -> 16 complex amps (wire0 = bit3)
    float w01r[4], w01i[4], w23r[4], w23i[4];
#pragma unroll
    for (int a = 0; a < 2; a++) {
#pragma unroll
        for (int c = 0; c < 2; c++) {
            w01r[a * 2 + c] = vr[0][a] * vr[1][c] - vi[0][a] * vi[1][c];
            w01i[a * 2 + c] = vr[0][a] * vi[1][c] + vi[0][a] * vr[1][c];
            w23r[a * 2 + c] = vr[2][a] * vr[3][c] - vi[2][a] * vi[3][c];
            w23i[a * 2 + c] = vr[2][a] * vi[3][c] + vi[2][a] * vr[3][c];
        }
    }
    float sr[16], si[16];
#pragma unroll
    for (int hi = 0; hi < 4; hi++) {
#pragma unroll
        for (int lo = 0; lo < 4; lo++) {
            sr[hi * 4 + lo] = w01r[hi] * w23r[lo] - w01i[hi] * w23i[lo];
            si[hi * 4 + lo] = w01r[hi] * w23i[lo] + w01i[hi] * w23r[lo];
        }
    }

    // psi = W * psi0 ; p_j = |psi_j|^2. W indices are compile-time constants
    // -> uniform address -> scalar loads; FMAs take the gate as SGPR operand.
    float p[16];
#pragma unroll
    for (int j = 0; j < 16; j++) {
        float prr = 0.0f, pii = 0.0f;
#pragma unroll
        for (int k = 0; k < 16; k++) {
            const float wr = W[(j * 16 + k) * 2 + 0];
            const float wv = W[(j * 16 + k) * 2 + 1];
            prr = fmaf(wr, sr[k], prr);
            prr = fmaf(-wv, si[k], prr);
            pii = fmaf(wr, si[k], pii);
            pii = fmaf(wv, sr[k], pii);
        }
        p[j] = prr * prr + pii * pii;
    }

    // butterfly signed reduction: bit0=wire3 ... bit3=wire0
    const float a0 = p[0] + p[1],   a1 = p[2] + p[3],   a2 = p[4] + p[5],   a3 = p[6] + p[7];
    const float a4 = p[8] + p[9],   a5 = p[10] + p[11], a6 = p[12] + p[13], a7 = p[14] + p[15];
    const float z3 = (p[0] - p[1]) + (p[2] - p[3]) + (p[4] - p[5]) + (p[6] - p[7])
                   + (p[8] - p[9]) + (p[10] - p[11]) + (p[12] - p[13]) + (p[14] - p[15]);
    const float b0 = a0 + a1, b1 = a2 + a3, b2 = a4 + a5, b3 = a6 + a7;
    const float z2 = (a0 - a1) + (a2 - a3) + (a4 - a5) + (a6 - a7);
    const float c0 = b0 + b1, c1 = b2 + b3;
    const float z1 = (b0 - b1) + (b2 - b3);
    const float z0 = c0 - c1;

    ((float4*)out)[b] = make_float4(z0, z1, z2, z3);
}

extern "C" void kernel_launch(void* const* d_in, const int* in_sizes, int n_in,
                              void* d_out, int out_size, void* d_ws, size_t ws_size,
                              hipStream_t stream) {
    const float* x = (const float*)d_in[0];   // [B,4] fp32
    const float* w = (const float*)d_in[1];   // [5,4,3] fp32
    float* out = (float*)d_out;               // [B,4] fp32
    float* W = (float*)d_ws;                  // 16*16*2 floats = 2 KB
    const int b = in_sizes[0] / 4;

    compose_W<<<1, 256, 0, stream>>>(w, W);
    qmain<<<b / 256, 256, 0, stream>>>(x, W, out);
}